// Round 6
// baseline (175.168 us; speedup 1.0000x reference)
//
#include <hip/hip_runtime.h>
#include <hip/hip_fp16.h>

#define N 1024
#define D 128

// ---------------- proj: Qh,Kh,Ah,Bh (all f16) = z@{Wq,Wk,W1a,W1b} ----------------
// 4 rows/block, 256 blocks -> 1024 waves = 1 wave/SIMD. Scale folded into Qh. (proven round 5)
__global__ __launch_bounds__(256) void proj_kernel(
    const float* __restrict__ z,
    const float* __restrict__ Wq, const float* __restrict__ bq,
    const float* __restrict__ Wk, const float* __restrict__ bk,
    const float* __restrict__ W1, const float* __restrict__ b1,
    __half* __restrict__ Qh, __half* __restrict__ Kh,
    __half* __restrict__ Ah, __half* __restrict__ Bh)
{
    const int d  = threadIdx.x & (D - 1);
    const int h  = threadIdx.x >> 7;              // wave-uniform: 0 -> Q/K, 1 -> A/B
    const int r0 = blockIdx.x * 4;
    const float* __restrict__ Wa = h ? W1           : Wq;
    const float* __restrict__ Wb = h ? (W1 + D * D) : Wk;

    float acc0[4] = {0,0,0,0};
    float acc1[4] = {0,0,0,0};

    for (int c = 0; c < D / 4; ++c) {
        float4 zr[4];
#pragma unroll
        for (int r = 0; r < 4; ++r)
            zr[r] = *(const float4*)&z[(r0 + r) * D + c * 4];
#pragma unroll
        for (int q = 0; q < 4; ++q) {
            const int k = c * 4 + q;
            const float wa = Wa[k * D + d];
            const float wb = Wb[k * D + d];
#pragma unroll
            for (int r = 0; r < 4; ++r) {
                const float zv = (q == 0) ? zr[r].x : (q == 1) ? zr[r].y : (q == 2) ? zr[r].z : zr[r].w;
                acc0[r] = fmaf(zv, wa, acc0[r]);
                acc1[r] = fmaf(zv, wb, acc1[r]);
            }
        }
    }
    if (h == 0) {
        const float c0 = bq[d], c1 = bk[d];
        const float scale = 0.08838834764831845f;   // 1/sqrt(128), folded into Qh
#pragma unroll
        for (int r = 0; r < 4; ++r) {
            Qh[(r0 + r) * D + d] = __float2half((acc0[r] + c0) * scale);
            Kh[(r0 + r) * D + d] = __float2half(acc1[r] + c1);
        }
    } else {
        const float c0 = b1[d];
#pragma unroll
        for (int r = 0; r < 4; ++r) {
            Ah[(r0 + r) * D + d] = __float2half(acc0[r] + c0);   // b1 folded
            Bh[(r0 + r) * D + d] = __float2half(acc1[r]);
        }
    }
}

union H2x4 { uint4 u; __half2 h[4]; };

__device__ __forceinline__ float fdot2_acc(__half2 a, __half2 b, float c) {
#if __has_builtin(__builtin_amdgcn_fdot2)
    typedef _Float16 v2h __attribute__((ext_vector_type(2)));
    union { __half2 h; v2h v; } ua, ub;
    ua.h = a; ub.h = b;
    return __builtin_amdgcn_fdot2(ua.v, ub.v, c, false);
#else
    return fmaf(__low2float(a), __low2float(b),
           fmaf(__high2float(a), __high2float(b), c));
#endif
}

// ---------------- fused scores + softmax + top-32: one wave per row ----------------
// S never touches HBM (was: score writes 4MB, topk reads+rewrites). Per block: 4 rows.
// Q row in VGPRs (wave-uniform). K staged in 64-row LDS chunks, XOR-swizzled
// (linear 256B row stride => all 64 lanes same bank on the per-lane row read;
// col^(row&15) balances to 8 accesses/bank = b128 floor). Next chunk's global
// loads issue before the current dot-loop (latency hidden under ~450cy of dots).
// v[16] per lane (j = e*64+lane) feeds the round-5-proven u32-key topk verbatim.
__global__ __launch_bounds__(256) void score_topk_kernel(
    const __half* __restrict__ Qh, const __half* __restrict__ Kh,
    const float* __restrict__ dist, float* __restrict__ out)
{
    __shared__ __align__(16) uint4 Ks[64 * 16];   // 16 KB, swizzled [row][col^...]
    const int tid  = threadIdx.x;
    const int lane = tid & 63;
    const int row  = blockIdx.x * 4 + (tid >> 6);

    // Q row -> registers (wave-uniform addresses -> broadcast-friendly)
    uint4 qreg[16];
#pragma unroll
    for (int k = 0; k < 16; ++k)
        qreg[k] = *(const uint4*)&Qh[(size_t)row * D + k * 8];

    // prologue: prefetch chunk 0
    uint4 pre[4];
#pragma unroll
    for (int t = 0; t < 4; ++t) {
        const int e = t * 256 + tid, r = e >> 4, col = e & 15;
        pre[t] = *(const uint4*)&Kh[(size_t)r * D + col * 8];
    }

    float v[16];
    for (int c = 0; c < 16; ++c) {
        __syncthreads();                           // prev chunk's LDS reads done
#pragma unroll
        for (int t = 0; t < 4; ++t) {
            const int e = t * 256 + tid, r = e >> 4, col = e & 15;
            Ks[r * 16 + (col ^ (r & 15))] = pre[t];
        }
        __syncthreads();
        if (c < 15) {                              // issue next chunk early (T14)
#pragma unroll
            for (int t = 0; t < 4; ++t) {
                const int e = t * 256 + tid, r = e >> 4, col = e & 15;
                pre[t] = *(const uint4*)&Kh[(size_t)((c + 1) * 64 + r) * D + col * 8];
            }
        }
        // dot(Q[row], K[c*64+lane]) ; 4 partial accs -> 4-way ILP on the fdot2 chain
        float s[4] = {0.f, 0.f, 0.f, 0.f};
#pragma unroll
        for (int k = 0; k < 4; ++k)
#pragma unroll
            for (int mm = 0; mm < 4; ++mm) {
                const int c8 = k * 4 + mm;
                H2x4 kk, qq;
                kk.u = Ks[lane * 16 + (c8 ^ (lane & 15))];
                qq.u = qreg[c8];
                s[k] = fdot2_acc(qq.h[0], kk.h[0], s[k]);
                s[k] = fdot2_acc(qq.h[1], kk.h[1], s[k]);
                s[k] = fdot2_acc(qq.h[2], kk.h[2], s[k]);
                s[k] = fdot2_acc(qq.h[3], kk.h[3], s[k]);
            }
        const int j = c * 64 + lane;
        v[c] = ((s[0] + s[1]) + (s[2] + s[3])) * __expf(-dist[(size_t)row * N + j]);
    }

    // ---- softmax + top-32 (round-5-proven, j = e*64+lane) ----
    float m = v[0];
#pragma unroll
    for (int e = 1; e < 16; ++e) m = fmaxf(m, v[e]);
#pragma unroll
    for (int off = 1; off < 64; off <<= 1) m = fmaxf(m, __shfl_xor(m, off));
    float sum = 0.f;
#pragma unroll
    for (int e = 0; e < 16; ++e) sum += __expf(v[e] - m);
#pragma unroll
    for (int off = 1; off < 64; off <<= 1) sum += __shfl_xor(sum, off);
    const float inv = 1.0f / sum;

    unsigned key[16];
#pragma unroll
    for (int e = 0; e < 16; ++e) {
        const int j = e * 64 + lane;
        unsigned u = __float_as_uint(v[e]);
        u = (u & 0x80000000u) ? ~u : (u | 0x80000000u);
        key[e] = (u & 0xFFFFFC00u) | (unsigned)(N - 1 - j);
    }
    unsigned flags = 0;
    for (int it = 0; it < 32; ++it) {
        unsigned best = key[0];
#pragma unroll
        for (int e = 1; e < 16; ++e) best = (key[e] > best) ? key[e] : best;
#pragma unroll
        for (int off = 1; off < 64; off <<= 1) {
            const unsigned o = __shfl_xor(best, off);
            if (o > best) best = o;
        }
#pragma unroll
        for (int e = 0; e < 16; ++e)
            if (key[e] == best) { flags |= 1u << e; key[e] = 0u; }
    }
#pragma unroll
    for (int e = 0; e < 16; ++e) {
        const float o = (flags & (1u << e)) ? __expf(v[e] - m) * inv : 0.f;
        out[(size_t)row * N + e * 64 + lane] = o;
    }
}

#define HP 136   // halves pitch: 272 B rows (16B-aligned); 2-way bank alias only (free)

// ---------------- pairwise gelu classifier + 3-way softmax (proven round 5, untouched) ----------------
__global__ __launch_bounds__(256) void pair_kernel(
    const __half* __restrict__ Ah, const __half* __restrict__ Bh,
    const float* __restrict__ W2, const float* __restrict__ b2,
    float* __restrict__ out)
{
    __shared__ __align__(16) __half AsH[32 * HP];
    __shared__ __align__(16) __half BsH[32 * HP];
    __shared__ __align__(16) __half2 Wh[2][68];
    const int tid = threadIdx.x;
    const int bi = blockIdx.y * 32, bj = blockIdx.x * 32;
    const int tx = tid & 15, ty = tid >> 4;

#pragma unroll
    for (int t = 0; t < 2; ++t) {
        const int e = t * 256 + tid;
        const int row = e >> 4, c = e & 15;
        *(uint4*)&AsH[row * HP + c * 8] = *(const uint4*)&Ah[(size_t)(bi + row) * D + c * 8];
        *(uint4*)&BsH[row * HP + c * 8] = *(const uint4*)&Bh[(size_t)(bj + row) * D + c * 8];
    }
    // Wh[cls][dp] = {W2[2dp][cls]-W2[2dp][2], W2[2dp+1][cls]-W2[2dp+1][2]}  (no 0.5!)
    if (tid < 128) {
        const int cls = tid >> 6, dp = tid & 63;
        Wh[cls][dp] = __floats2half2_rn(W2[6 * dp + cls]     - W2[6 * dp + 2],
                                        W2[6 * dp + 3 + cls] - W2[6 * dp + 5]);
    }
    const float bb0 = b2[0] - b2[2], bb1 = b2[1] - b2[2];
    __syncthreads();

    float acc[4][2];                    // [site=ii*2+jj][class 0,1]; class-2 logit == 0
#pragma unroll
    for (int p = 0; p < 4; ++p) { acc[p][0] = bb0; acc[p][1] = bb1; }

    const __half2 C3  = __float2half2_rn(-0.1029434f);
    const __half2 C1  = __float2half2_rn(-2.3022082f);
    const __half2 ONE = __float2half2_rn(1.0f);

#pragma unroll 4
    for (int c = 0; c < 16; ++c) {      // 16 chunks x 8 d
        H2x4 a0, a1, b0, b1, w0, w1;
        a0.u = *(const uint4*)&AsH[ty * HP + c * 8];
        a1.u = *(const uint4*)&AsH[(ty + 16) * HP + c * 8];
        b0.u = *(const uint4*)&BsH[tx * HP + c * 8];
        b1.u = *(const uint4*)&BsH[(tx + 16) * HP + c * 8];
        w0.u = *(const uint4*)&Wh[0][c * 4];    // wave-uniform -> LDS broadcast
        w1.u = *(const uint4*)&Wh[1][c * 4];
#pragma unroll
        for (int dp = 0; dp < 4; ++dp) {
            const __half2 aa[2] = { a0.h[dp], a1.h[dp] };
            const __half2 bb[2] = { b0.h[dp], b1.h[dp] };
            const __half2 wc0 = w0.h[dp], wc1 = w1.h[dp];
#pragma unroll
            for (int ii = 0; ii < 2; ++ii)
#pragma unroll
                for (int jj = 0; jj < 2; ++jj) {
                    const __half2 x = __hadd2(aa[ii], bb[jj]);
                    const __half2 u = __hmul2(x, x);
                    const __half2 p = __hfma2(C3, u, C1);
                    const __half2 t = __hmul2(x, p);
                    const __half2 e = h2exp2(t);          // 2^t ; under/overflow -> 0/inf (correct limits)
                    const __half2 dn = __hadd2(e, ONE);
                    const __half2 r = h2rcp(dn);          // rcp(inf)=0 -> g=0 (correct)
                    const __half2 g = __hmul2(x, r);      // g = gelu(x)
                    float* l = acc[ii * 2 + jj];
                    l[0] = fdot2_acc(g, wc0, l[0]);
                    l[1] = fdot2_acc(g, wc1, l[1]);
                }
        }
    }

#pragma unroll
    for (int ii = 0; ii < 2; ++ii)
#pragma unroll
        for (int jj = 0; jj < 2; ++jj) {
            const int i = bi + ty + 16 * ii;
            const int j = bj + tx + 16 * jj;
            const float* l = acc[ii * 2 + jj];
            const float l0 = l[0], l1 = l[1];                // l2 == 0
            const float mm = fmaxf(fmaxf(l0, l1), 0.f);
            const float e0 = __expf(l0 - mm), e1 = __expf(l1 - mm), e2 = __expf(-mm);
            const float inv2 = 1.0f / (e0 + e1 + e2);
            float* o = out + ((size_t)i * N + j) * 3;
            o[0] = e0 * inv2; o[1] = e1 * inv2; o[2] = e2 * inv2;
        }
}

extern "C" void kernel_launch(void* const* d_in, const int* in_sizes, int n_in,
                              void* d_out, int out_size, void* d_ws, size_t ws_size,
                              hipStream_t stream)
{
    const float* z    = (const float*)d_in[0];
    const float* dist = (const float*)d_in[1];
    const float* Wq   = (const float*)d_in[2];
    const float* bq   = (const float*)d_in[3];
    const float* Wk   = (const float*)d_in[4];
    const float* bk   = (const float*)d_in[5];
    const float* W1   = (const float*)d_in[6];
    const float* b1   = (const float*)d_in[7];
    const float* W2   = (const float*)d_in[8];
    const float* b2   = (const float*)d_in[9];

    float* out = (float*)d_out;
    __half* Qh = (__half*)d_ws;
    __half* Kh = Qh + (size_t)N * D;
    __half* Ah = Kh + (size_t)N * D;
    __half* Bh = Ah + (size_t)N * D;

    proj_kernel<<<N / 4, 256, 0, stream>>>(z, Wq, bq, Wk, bk, W1, b1, Qh, Kh, Ah, Bh);
    score_topk_kernel<<<N / 4, 256, 0, stream>>>(Qh, Kh, dist, out);
    pair_kernel<<<dim3(N / 32, N / 32), 256, 0, stream>>>(Ah, Bh, W2, b2, out + (size_t)N * N);
}